// Round 2
// baseline (2218.232 us; speedup 1.0000x reference)
//
#include <hip/hip_runtime.h>

#define N_NODES 100000
#define E_EDGES 1000000
#define F_IN    128
#define HID     64
#define OUT_F   40
#define LAYERS  4
#define ALPHA   0.5f
#define BN_EPS  1e-5f

// ---------- degree / norm ----------
__global__ __launch_bounds__(256) void k_deg_init(float* __restrict__ deg) {
    int i = blockIdx.x * 256 + threadIdx.x;
    if (i < N_NODES) deg[i] = 1.0f;   // self-loop contributes 1
}

__global__ __launch_bounds__(256) void k_deg_count(const int* __restrict__ col,
                                                   float* __restrict__ deg) {
    int e = blockIdx.x * 256 + threadIdx.x;
    if (e < E_EDGES) atomicAdd(&deg[col[e]], 1.0f);
}

__global__ __launch_bounds__(256) void k_dinv(float* __restrict__ deg) {
    int i = blockIdx.x * 256 + threadIdx.x;
    if (i < N_NODES) deg[i] = rsqrtf(deg[i]);   // deg >= 1 always
}

// ---------- input layer: h = relu(x @ Wi + bi), write h0 and hprev ----------
__global__ __launch_bounds__(256) void k_input(const float* __restrict__ x,
                                               const float* __restrict__ Wi,
                                               const float* __restrict__ bi,
                                               float* __restrict__ h0,
                                               float* __restrict__ hprev) {
    __shared__ float wis[F_IN * HID];           // 32 KB
    for (int i = threadIdx.x; i < F_IN * HID; i += 256) wis[i] = Wi[i];
    __syncthreads();
    int wave = threadIdx.x >> 6, lane = threadIdx.x & 63;
    float bias = bi[lane];
    for (int n = blockIdx.x * 4 + wave; n < N_NODES; n += gridDim.x * 4) {
        float xlo = x[n * F_IN + lane];
        float xhi = x[n * F_IN + 64 + lane];
        float acc = bias;
        #pragma unroll 16
        for (int k = 0; k < 64; ++k)
            acc = fmaf(__shfl(xlo, k, 64), wis[k * HID + lane], acc);
        #pragma unroll 16
        for (int k = 0; k < 64; ++k)
            acc = fmaf(__shfl(xhi, k, 64), wis[(64 + k) * HID + lane], acc);
        float h = fmaxf(acc, 0.0f);
        h0[n * HID + lane] = h;
        hprev[n * HID + lane] = h;
    }
}

// ---------- per-layer dense part:
// support = hprev + hprev@W1 ; agg = (alpha*h0 + h0@W2) + dinv^2 * support ----------
__global__ __launch_bounds__(256) void k_layerA(const float* __restrict__ hprev,
                                                const float* __restrict__ h0,
                                                const float* __restrict__ w1,
                                                const float* __restrict__ w2,
                                                const float* __restrict__ dinv,
                                                float* __restrict__ support,
                                                float* __restrict__ agg) {
    __shared__ float w1s[HID * HID];            // 16 KB
    __shared__ float w2s[HID * HID];            // 16 KB
    for (int i = threadIdx.x; i < HID * HID; i += 256) {
        w1s[i] = w1[i];
        w2s[i] = w2[i];
    }
    __syncthreads();
    int wave = threadIdx.x >> 6, lane = threadIdx.x & 63;
    for (int n = blockIdx.x * 4 + wave; n < N_NODES; n += gridDim.x * 4) {
        float hp = hprev[n * HID + lane];
        float hz = h0[n * HID + lane];
        float a1 = 0.0f, a2 = 0.0f;
        #pragma unroll 16
        for (int k = 0; k < HID; ++k) {
            a1 = fmaf(__shfl(hp, k, 64), w1s[k * HID + lane], a1);
            a2 = fmaf(__shfl(hz, k, 64), w2s[k * HID + lane], a2);
        }
        float s   = hp + a1;
        float ini = ALPHA * hz + a2;
        float dv  = dinv[n];
        support[n * HID + lane] = s;
        agg[n * HID + lane] = ini + dv * dv * s;   // self-loop folded in
    }
}

// ---------- edge scatter: agg[col] += dinv[row]*dinv[col] * support[row] ----------
__global__ __launch_bounds__(256) void k_scatter(const int* __restrict__ ei,
                                                 const float* __restrict__ dinv,
                                                 const float* __restrict__ support,
                                                 float* __restrict__ agg) {
    int lane = threadIdx.x & 63;
    int e = blockIdx.x * 4 + (threadIdx.x >> 6);
    if (e >= E_EDGES) return;
    int r = ei[e];
    int c = ei[E_EDGES + e];
    float nrm = dinv[r] * dinv[c];
    atomicAdd(&agg[c * HID + lane], nrm * support[r * HID + lane]);
}

// ---------- BN statistics: per-feature sum / sumsq over all nodes ----------
__global__ __launch_bounds__(256) void k_bnreduce(const float* __restrict__ agg,
                                                  float* __restrict__ sums) {
    __shared__ float ls[4][HID];
    __shared__ float lq[4][HID];
    int lane = threadIdx.x & 63, grp = threadIdx.x >> 6;
    float s = 0.0f, q = 0.0f;
    for (int n = blockIdx.x * 4 + grp; n < N_NODES; n += gridDim.x * 4) {
        float a = agg[n * HID + lane];
        s += a;
        q = fmaf(a, a, q);
    }
    ls[grp][lane] = s;
    lq[grp][lane] = q;
    __syncthreads();
    if (threadIdx.x < HID) {
        float ts = ls[0][lane] + ls[1][lane] + ls[2][lane] + ls[3][lane];
        float tq = lq[0][lane] + lq[1][lane] + lq[2][lane] + lq[3][lane];
        atomicAdd(&sums[lane], ts);
        atomicAdd(&sums[HID + lane], tq);
    }
}

// ---------- BN apply + relu + residual: hprev += relu(bn(agg)) ----------
__global__ __launch_bounds__(256) void k_bnapply(const float* __restrict__ agg,
                                                 const float* __restrict__ sums,
                                                 const float* __restrict__ gamma,
                                                 const float* __restrict__ beta,
                                                 float* __restrict__ hprev) {
    const float invN = 1.0f / (float)N_NODES;
    long total = (long)N_NODES * HID;
    for (long i = blockIdx.x * 256L + threadIdx.x; i < total; i += (long)gridDim.x * 256L) {
        int f = (int)(i & 63);
        float m = sums[f] * invN;
        float v = sums[HID + f] * invN - m * m;
        float a = agg[i];
        float o = gamma[f] * (a - m) * rsqrtf(v + BN_EPS) + beta[f];
        hprev[i] += fmaxf(o, 0.0f);
    }
}

// ---------- output GEMM: out = hprev @ Wo + bo ----------
__global__ __launch_bounds__(256) void k_out(const float* __restrict__ hprev,
                                             const float* __restrict__ Wo,
                                             const float* __restrict__ bo,
                                             float* __restrict__ out) {
    __shared__ float wos[HID * OUT_F];          // 10 KB
    __shared__ float bos[OUT_F];
    for (int i = threadIdx.x; i < HID * OUT_F; i += 256) wos[i] = Wo[i];
    if (threadIdx.x < OUT_F) bos[threadIdx.x] = bo[threadIdx.x];
    __syncthreads();
    long total = (long)N_NODES * OUT_F;
    for (long i = blockIdx.x * 256L + threadIdx.x; i < total; i += (long)gridDim.x * 256L) {
        int n = (int)(i / OUT_F);
        int o = (int)(i % OUT_F);
        float acc = bos[o];
        #pragma unroll 16
        for (int k = 0; k < HID; ++k)
            acc = fmaf(hprev[n * HID + k], wos[k * OUT_F + o], acc);
        out[i] = acc;
    }
}

extern "C" void kernel_launch(void* const* d_in, const int* in_sizes, int n_in,
                              void* d_out, int out_size, void* d_ws, size_t ws_size,
                              hipStream_t stream) {
    const float* x     = (const float*)d_in[0];
    const int*   ei    = (const int*)  d_in[1];   // [2, E]: row then col
    const float* Wi    = (const float*)d_in[2];
    const float* bi    = (const float*)d_in[3];
    const float* w1    = (const float*)d_in[4];
    const float* w2    = (const float*)d_in[5];
    const float* gamma = (const float*)d_in[6];
    const float* beta  = (const float*)d_in[7];
    const float* Wo    = (const float*)d_in[8];
    const float* bo    = (const float*)d_in[9];
    float* out = (float*)d_out;

    char* ws = (char*)d_ws;
    const size_t NH = (size_t)N_NODES * HID * sizeof(float);      // 25.6 MB
    size_t off = 0;
    float* dinv    = (float*)(ws + off); off += ((size_t)N_NODES * sizeof(float) + 255) & ~255UL;
    float* support = (float*)(ws + off); off += (NH + 255) & ~255UL;
    float* agg     = (float*)(ws + off); off += (NH + 255) & ~255UL;
    float* h0      = (float*)(ws + off); off += (NH + 255) & ~255UL;
    float* hprev   = (float*)(ws + off); off += (NH + 255) & ~255UL;
    float* sums    = (float*)(ws + off); off += LAYERS * 128 * sizeof(float);
    (void)ws_size; (void)in_sizes; (void)n_in; (void)out_size;

    // zero all per-layer BN accumulators once
    hipMemsetAsync(sums, 0, LAYERS * 128 * sizeof(float), stream);

    k_deg_init <<<(N_NODES + 255) / 256, 256, 0, stream>>>(dinv);
    k_deg_count<<<(E_EDGES + 255) / 256, 256, 0, stream>>>(ei + E_EDGES, dinv);
    k_dinv     <<<(N_NODES + 255) / 256, 256, 0, stream>>>(dinv);

    k_input<<<2048, 256, 0, stream>>>(x, Wi, bi, h0, hprev);

    for (int l = 0; l < LAYERS; ++l) {
        k_layerA  <<<2048, 256, 0, stream>>>(hprev, h0,
                                             w1 + (size_t)l * HID * HID,
                                             w2 + (size_t)l * HID * HID,
                                             dinv, support, agg);
        k_scatter <<<(E_EDGES + 3) / 4, 256, 0, stream>>>(ei, dinv, support, agg);
        k_bnreduce<<<1024, 256, 0, stream>>>(agg, sums + l * 128);
        k_bnapply <<<2048, 256, 0, stream>>>(agg, sums + l * 128,
                                             gamma + l * HID, beta + l * HID, hprev);
    }

    k_out<<<2048, 256, 0, stream>>>(hprev, Wo, bo, out);
}

// Round 3
// 1850.210 us; speedup vs baseline: 1.1989x; 1.1989x over previous
//
#include <hip/hip_runtime.h>

#define N_NODES 100000
#define E_EDGES 1000000
#define F_IN    128
#define HID     64
#define OUT_F   40
#define LAYERS  4
#define ALPHA   0.5f
#define BN_EPS  1e-5f

// ---------- CSR build ----------
__global__ __launch_bounds__(256) void k_deg_count(const int* __restrict__ col,
                                                   int* __restrict__ degInt) {
    int e = blockIdx.x * 256 + threadIdx.x;
    if (e < E_EDGES) atomicAdd(&degInt[col[e]], 1);
}

// single block, 1024 threads: exclusive scan of degInt -> rowOff (+cursor copy)
__global__ __launch_bounds__(1024) void k_scan(const int* __restrict__ degInt,
                                               int* __restrict__ rowOff,
                                               int* __restrict__ cursor) {
    __shared__ int part[1024];
    const int CH = (N_NODES + 1023) / 1024;   // 98
    int t = threadIdx.x;
    int start = t * CH, end = min(start + CH, N_NODES);
    int s = 0;
    for (int i = start; i < end; ++i) s += degInt[i];
    part[t] = s;
    __syncthreads();
    // Hillis-Steele inclusive scan
    for (int d = 1; d < 1024; d <<= 1) {
        int v = (t >= d) ? part[t - d] : 0;
        __syncthreads();
        part[t] += v;
        __syncthreads();
    }
    int running = part[t] - s;               // exclusive prefix
    for (int i = start; i < end; ++i) {
        rowOff[i] = running;
        cursor[i] = running;
        running += degInt[i];
    }
    if (start < N_NODES && end == N_NODES) rowOff[N_NODES] = running;  // == E
}

__global__ __launch_bounds__(256) void k_dinv(const int* __restrict__ degInt,
                                              float* __restrict__ dinv) {
    int i = blockIdx.x * 256 + threadIdx.x;
    if (i < N_NODES) dinv[i] = rsqrtf((float)(degInt[i] + 1));  // +1 self loop
}

__global__ __launch_bounds__(256) void k_fill(const int* __restrict__ ei,
                                              int* __restrict__ cursor,
                                              int* __restrict__ srow) {
    int e = blockIdx.x * 256 + threadIdx.x;
    if (e >= E_EDGES) return;
    int r = ei[e];
    int c = ei[E_EDGES + e];
    int pos = atomicAdd(&cursor[c], 1);
    srow[pos] = r;
}

// ---------- input layer: h = relu(x @ Wi + bi) -> h0, hprev ----------
__global__ __launch_bounds__(256) void k_input(const float* __restrict__ x,
                                               const float* __restrict__ Wi,
                                               const float* __restrict__ bi,
                                               float* __restrict__ h0,
                                               float* __restrict__ hprev) {
    __shared__ float wis[F_IN * HID];
    for (int i = threadIdx.x; i < F_IN * HID; i += 256) wis[i] = Wi[i];
    __syncthreads();
    int wave = threadIdx.x >> 6, lane = threadIdx.x & 63;
    float bias = bi[lane];
    for (int n = blockIdx.x * 4 + wave; n < N_NODES; n += gridDim.x * 4) {
        float xlo = x[(size_t)n * F_IN + lane];
        float xhi = x[(size_t)n * F_IN + 64 + lane];
        float acc = bias;
        #pragma unroll 16
        for (int k = 0; k < 64; ++k)
            acc = fmaf(__shfl(xlo, k, 64), wis[k * HID + lane], acc);
        #pragma unroll 16
        for (int k = 0; k < 64; ++k)
            acc = fmaf(__shfl(xhi, k, 64), wis[(64 + k) * HID + lane], acc);
        float h = fmaxf(acc, 0.0f);
        h0[(size_t)n * HID + lane] = h;
        hprev[(size_t)n * HID + lane] = h;
    }
}

// ---------- per-layer dense part (optionally applying previous layer's BN first):
// if apply_bn: hprev += relu(bn_prev(agg)); then
// support = hprev + hprev@W1 ; agg = (alpha*h0 + h0@W2) + dinv^2 * support ----------
__global__ __launch_bounds__(256) void k_layerA(float* __restrict__ hprev,
                                                const float* __restrict__ h0,
                                                float* agg,                   // r/w (prev result in, init out)
                                                const float* __restrict__ sums_prev,
                                                const float* __restrict__ gamma,
                                                const float* __restrict__ beta,
                                                int apply_bn,
                                                const float* __restrict__ w1,
                                                const float* __restrict__ w2,
                                                const float* __restrict__ dinv,
                                                float* __restrict__ support) {
    __shared__ float w1s[HID * HID];
    __shared__ float w2s[HID * HID];
    for (int i = threadIdx.x; i < HID * HID; i += 256) {
        w1s[i] = w1[i];
        w2s[i] = w2[i];
    }
    __syncthreads();
    int wave = threadIdx.x >> 6, lane = threadIdx.x & 63;
    const float invN = 1.0f / (float)N_NODES;
    float m = 0.f, inv = 0.f, g = 0.f, b = 0.f;
    if (apply_bn) {
        float mm = sums_prev[lane] * invN;
        float vv = sums_prev[HID + lane] * invN - mm * mm;
        m = mm; inv = rsqrtf(vv + BN_EPS);
        g = gamma[lane]; b = beta[lane];
    }
    for (int n = blockIdx.x * 4 + wave; n < N_NODES; n += gridDim.x * 4) {
        size_t idx = (size_t)n * HID + lane;
        float hp = hprev[idx];
        if (apply_bn) {
            float a = agg[idx];
            float o = g * (a - m) * inv + b;
            hp += fmaxf(o, 0.0f);
            hprev[idx] = hp;
        }
        float hz = h0[idx];
        float a1 = 0.0f, a2 = 0.0f;
        #pragma unroll 16
        for (int k = 0; k < HID; ++k) {
            a1 = fmaf(__shfl(hp, k, 64), w1s[k * HID + lane], a1);
            a2 = fmaf(__shfl(hz, k, 64), w2s[k * HID + lane], a2);
        }
        float s   = hp + a1;
        float ini = ALPHA * hz + a2;
        float dv  = dinv[n];
        support[idx] = s;
        agg[idx] = ini + dv * dv * s;      // self-loop folded in
    }
}

// ---------- gather aggregation + fused BN statistics ----------
// agg[c] += dinv[c] * sum_{e in CSR[c]} dinv[r_e] * support[r_e]; stats of final agg
__global__ __launch_bounds__(256) void k_gather(const int* __restrict__ rowOff,
                                                const int* __restrict__ srow,
                                                const float* __restrict__ dinv,
                                                const float* __restrict__ support,
                                                float* __restrict__ agg,
                                                float* __restrict__ sums) {
    __shared__ float ls[4][HID];
    __shared__ float lq[4][HID];
    int lane = threadIdx.x & 63, w = threadIdx.x >> 6;
    int wg = blockIdx.x * 4 + w;
    int nw = gridDim.x * 4;
    float s = 0.0f, q = 0.0f;
    for (int n = wg; n < N_NODES; n += nw) {
        int o0 = rowOff[n], o1 = rowOff[n + 1];
        float acc0 = 0.0f, acc1 = 0.0f;
        int e = o0;
        for (; e + 1 < o1; e += 2) {
            int r0 = srow[e], r1 = srow[e + 1];
            acc0 = fmaf(dinv[r0], support[(size_t)r0 * HID + lane], acc0);
            acc1 = fmaf(dinv[r1], support[(size_t)r1 * HID + lane], acc1);
        }
        if (e < o1) {
            int r = srow[e];
            acc0 = fmaf(dinv[r], support[(size_t)r * HID + lane], acc0);
        }
        float dv = dinv[n];
        size_t idx = (size_t)n * HID + lane;
        float a = agg[idx] + dv * (acc0 + acc1);
        agg[idx] = a;
        s += a;
        q = fmaf(a, a, q);
    }
    ls[w][lane] = s;
    lq[w][lane] = q;
    __syncthreads();
    if (threadIdx.x < HID) {
        float ts = ls[0][lane] + ls[1][lane] + ls[2][lane] + ls[3][lane];
        float tq = lq[0][lane] + lq[1][lane] + lq[2][lane] + lq[3][lane];
        atomicAdd(&sums[lane], ts);
        atomicAdd(&sums[HID + lane], tq);
    }
}

// ---------- output: h = hprev + relu(bn3(agg)); out = h @ Wo + bo ----------
__global__ __launch_bounds__(256) void k_out(const float* __restrict__ hprev,
                                             const float* __restrict__ agg,
                                             const float* __restrict__ sums,
                                             const float* __restrict__ gamma,
                                             const float* __restrict__ beta,
                                             const float* __restrict__ Wo,
                                             const float* __restrict__ bo,
                                             float* __restrict__ out) {
    __shared__ float wos[HID * 64];   // padded to 64 cols
    __shared__ float bos[64];
    for (int i = threadIdx.x; i < HID * 64; i += 256) wos[i] = 0.0f;
    __syncthreads();
    for (int i = threadIdx.x; i < HID * OUT_F; i += 256)
        wos[(i / OUT_F) * 64 + (i % OUT_F)] = Wo[i];
    if (threadIdx.x < 64) bos[threadIdx.x] = (threadIdx.x < OUT_F) ? bo[threadIdx.x] : 0.0f;
    __syncthreads();
    int wave = threadIdx.x >> 6, lane = threadIdx.x & 63;
    const float invN = 1.0f / (float)N_NODES;
    float mm = sums[lane] * invN;
    float vv = sums[HID + lane] * invN - mm * mm;
    float inv = rsqrtf(vv + BN_EPS);
    float g = gamma[lane], b = beta[lane];
    for (int n = blockIdx.x * 4 + wave; n < N_NODES; n += gridDim.x * 4) {
        size_t idx = (size_t)n * HID + lane;
        float a = agg[idx];
        float o = g * (a - mm) * inv + b;
        float h = hprev[idx] + fmaxf(o, 0.0f);
        float acc = bos[lane];
        #pragma unroll 16
        for (int k = 0; k < HID; ++k)
            acc = fmaf(__shfl(h, k, 64), wos[k * 64 + lane], acc);
        if (lane < OUT_F) out[(size_t)n * OUT_F + lane] = acc;
    }
}

extern "C" void kernel_launch(void* const* d_in, const int* in_sizes, int n_in,
                              void* d_out, int out_size, void* d_ws, size_t ws_size,
                              hipStream_t stream) {
    const float* x     = (const float*)d_in[0];
    const int*   ei    = (const int*)  d_in[1];   // [2, E]: row then col
    const float* Wi    = (const float*)d_in[2];
    const float* bi    = (const float*)d_in[3];
    const float* w1    = (const float*)d_in[4];
    const float* w2    = (const float*)d_in[5];
    const float* gamma = (const float*)d_in[6];
    const float* beta  = (const float*)d_in[7];
    const float* Wo    = (const float*)d_in[8];
    const float* bo    = (const float*)d_in[9];
    float* out = (float*)d_out;

    char* ws = (char*)d_ws;
    const size_t NH = (size_t)N_NODES * HID * sizeof(float);      // 25.6 MB
    size_t off = 0;
    auto alloc = [&](size_t bytes) { void* p = ws + off; off += (bytes + 255) & ~255UL; return p; };
    int*   degInt = (int*)  alloc(N_NODES * sizeof(int));
    int*   rowOff = (int*)  alloc((N_NODES + 1) * sizeof(int));
    int*   cursor = (int*)  alloc(N_NODES * sizeof(int));
    int*   srow   = (int*)  alloc(E_EDGES * sizeof(int));
    float* dinv   = (float*)alloc(N_NODES * sizeof(float));
    float* support= (float*)alloc(NH);
    float* agg    = (float*)alloc(NH);
    float* h0     = (float*)alloc(NH);
    float* hprev  = (float*)alloc(NH);
    float* sums   = (float*)alloc(LAYERS * 128 * sizeof(float));
    (void)ws_size; (void)in_sizes; (void)n_in; (void)out_size;

    hipMemsetAsync(degInt, 0, N_NODES * sizeof(int), stream);
    hipMemsetAsync(sums, 0, LAYERS * 128 * sizeof(float), stream);

    k_deg_count<<<(E_EDGES + 255) / 256, 256, 0, stream>>>(ei + E_EDGES, degInt);
    k_scan     <<<1, 1024, 0, stream>>>(degInt, rowOff, cursor);
    k_dinv     <<<(N_NODES + 255) / 256, 256, 0, stream>>>(degInt, dinv);
    k_fill     <<<(E_EDGES + 255) / 256, 256, 0, stream>>>(ei, cursor, srow);

    k_input<<<2048, 256, 0, stream>>>(x, Wi, bi, h0, hprev);

    for (int l = 0; l < LAYERS; ++l) {
        const float* sums_prev = (l > 0) ? (sums + (l - 1) * 128) : sums;
        const float* gm        = (l > 0) ? (gamma + (l - 1) * HID) : gamma;
        const float* bt        = (l > 0) ? (beta  + (l - 1) * HID) : beta;
        k_layerA<<<2048, 256, 0, stream>>>(hprev, h0, agg, sums_prev, gm, bt, (l > 0),
                                           w1 + (size_t)l * HID * HID,
                                           w2 + (size_t)l * HID * HID,
                                           dinv, support);
        k_gather<<<2048, 256, 0, stream>>>(rowOff, srow, dinv, support, agg,
                                           sums + l * 128);
    }

    k_out<<<2048, 256, 0, stream>>>(hprev, agg, sums + 3 * 128,
                                    gamma + 3 * HID, beta + 3 * HID, Wo, bo, out);
}

// Round 4
// 1586.459 us; speedup vs baseline: 1.3982x; 1.1663x over previous
//
#include <hip/hip_runtime.h>

#define N_NODES 100000
#define E_EDGES 1000000
#define F_IN    128
#define HID     64
#define OUT_F   40
#define LAYERS  4
#define ALPHA   0.5f
#define BN_EPS  1e-5f

#define SCAN_BLOCKS ((N_NODES + 255) / 256)   // 391

// ---------- CSR build ----------
__global__ __launch_bounds__(256) void k_deg_count(const int* __restrict__ col,
                                                   int* __restrict__ degInt) {
    int e = blockIdx.x * 256 + threadIdx.x;
    if (e < E_EDGES) atomicAdd(&degInt[col[e]], 1);
}

// per-block inclusive scan of degInt; block totals out
__global__ __launch_bounds__(256) void k_scanA(const int* __restrict__ degInt,
                                               int* __restrict__ tmpIncl,
                                               int* __restrict__ blockSums) {
    __shared__ int sm[256];
    int i = blockIdx.x * 256 + threadIdx.x;
    int v = (i < N_NODES) ? degInt[i] : 0;
    sm[threadIdx.x] = v;
    __syncthreads();
    for (int d = 1; d < 256; d <<= 1) {
        int t = (threadIdx.x >= d) ? sm[threadIdx.x - d] : 0;
        __syncthreads();
        sm[threadIdx.x] += t;
        __syncthreads();
    }
    if (i < N_NODES) tmpIncl[i] = sm[threadIdx.x];
    if (threadIdx.x == 255) blockSums[blockIdx.x] = sm[255];
}

// single block: exclusive scan of the 391 block sums
__global__ __launch_bounds__(512) void k_scanB(int* __restrict__ blockSums,
                                               int* __restrict__ blockOff) {
    __shared__ int sm[512];
    int t = threadIdx.x;
    int v = (t < SCAN_BLOCKS) ? blockSums[t] : 0;
    sm[t] = v;
    __syncthreads();
    for (int d = 1; d < 512; d <<= 1) {
        int u = (t >= d) ? sm[t - d] : 0;
        __syncthreads();
        sm[t] += u;
        __syncthreads();
    }
    if (t < SCAN_BLOCKS) blockOff[t] = sm[t] - v;   // exclusive
}

// combine: rowOff/cursor/dinv; rowOff[N] = E
__global__ __launch_bounds__(256) void k_scanC(const int* __restrict__ degInt,
                                               const int* __restrict__ tmpIncl,
                                               const int* __restrict__ blockOff,
                                               int* __restrict__ rowOff,
                                               int* __restrict__ cursor,
                                               float* __restrict__ dinv) {
    int i = blockIdx.x * 256 + threadIdx.x;
    if (i >= N_NODES) return;
    int d = degInt[i];
    int incl = tmpIncl[i] + blockOff[blockIdx.x];
    int excl = incl - d;
    rowOff[i] = excl;
    cursor[i] = excl;
    dinv[i] = rsqrtf((float)(d + 1));               // +1 self loop
    if (i == N_NODES - 1) rowOff[N_NODES] = incl;   // == E
}

__global__ __launch_bounds__(256) void k_fill(const int* __restrict__ ei,
                                              int* __restrict__ cursor,
                                              int* __restrict__ srow) {
    int e = blockIdx.x * 256 + threadIdx.x;
    if (e >= E_EDGES) return;
    int r = ei[e];
    int c = ei[E_EDGES + e];
    int pos = atomicAdd(&cursor[c], 1);
    srow[pos] = r;
}

// ---------- input layer: h = relu(x @ Wi + bi) -> h0, hprev ----------
__global__ __launch_bounds__(256) void k_input(const float* __restrict__ x,
                                               const float* __restrict__ Wi,
                                               const float* __restrict__ bi,
                                               float* __restrict__ h0,
                                               float* __restrict__ hprev) {
    __shared__ float wis[F_IN * HID];
    for (int i = threadIdx.x; i < F_IN * HID; i += 256) wis[i] = Wi[i];
    __syncthreads();
    int wave = threadIdx.x >> 6, lane = threadIdx.x & 63;
    float bias = bi[lane];
    for (int n = blockIdx.x * 4 + wave; n < N_NODES; n += gridDim.x * 4) {
        float xlo = x[(size_t)n * F_IN + lane];
        float xhi = x[(size_t)n * F_IN + 64 + lane];
        float acc = bias;
        #pragma unroll 16
        for (int k = 0; k < 64; ++k)
            acc = fmaf(__shfl(xlo, k, 64), wis[k * HID + lane], acc);
        #pragma unroll 16
        for (int k = 0; k < 64; ++k)
            acc = fmaf(__shfl(xhi, k, 64), wis[(64 + k) * HID + lane], acc);
        float h = fmaxf(acc, 0.0f);
        h0[(size_t)n * HID + lane] = h;
        hprev[(size_t)n * HID + lane] = h;
    }
}

// ---------- per-layer dense part (optionally applying previous layer's BN first):
// if apply_bn: hprev += relu(bn_prev(agg)); then
// support = hprev + hprev@W1 ; sscaled = dinv[n]*support
// agg = (alpha*h0 + h0@W2) + dinv[n]*sscaled     (self-loop folded in) ----------
__global__ __launch_bounds__(256) void k_layerA(float* __restrict__ hprev,
                                                const float* __restrict__ h0,
                                                float* agg,
                                                const float* __restrict__ sums_prev,
                                                const float* __restrict__ gamma,
                                                const float* __restrict__ beta,
                                                int apply_bn,
                                                const float* __restrict__ w1,
                                                const float* __restrict__ w2,
                                                const float* __restrict__ dinv,
                                                float* __restrict__ sscaled) {
    __shared__ float w1s[HID * HID];
    __shared__ float w2s[HID * HID];
    for (int i = threadIdx.x; i < HID * HID; i += 256) {
        w1s[i] = w1[i];
        w2s[i] = w2[i];
    }
    __syncthreads();
    int wave = threadIdx.x >> 6, lane = threadIdx.x & 63;
    const float invN = 1.0f / (float)N_NODES;
    float m = 0.f, inv = 0.f, g = 0.f, b = 0.f;
    if (apply_bn) {
        float mm = sums_prev[lane] * invN;
        float vv = sums_prev[HID + lane] * invN - mm * mm;
        m = mm; inv = rsqrtf(vv + BN_EPS);
        g = gamma[lane]; b = beta[lane];
    }
    for (int n = blockIdx.x * 4 + wave; n < N_NODES; n += gridDim.x * 4) {
        size_t idx = (size_t)n * HID + lane;
        float hp = hprev[idx];
        if (apply_bn) {
            float a = agg[idx];
            float o = g * (a - m) * inv + b;
            hp += fmaxf(o, 0.0f);
            hprev[idx] = hp;
        }
        float hz = h0[idx];
        float a1 = 0.0f, a2 = 0.0f;
        #pragma unroll 16
        for (int k = 0; k < HID; ++k) {
            a1 = fmaf(__shfl(hp, k, 64), w1s[k * HID + lane], a1);
            a2 = fmaf(__shfl(hz, k, 64), w2s[k * HID + lane], a2);
        }
        float dv  = dinv[n];
        float ss  = dv * (hp + a1);               // dinv[n] * support
        float ini = ALPHA * hz + a2;
        sscaled[idx] = ss;
        agg[idx] = ini + dv * ss;
    }
}

// ---------- gather aggregation + fused BN statistics ----------
// agg[c] += dinv[c] * sum_{e in CSR[c]} sscaled[r_e]; stats of final agg
__global__ __launch_bounds__(256) void k_gather(const int* __restrict__ rowOff,
                                                const int* __restrict__ srow,
                                                const float* __restrict__ dinv,
                                                const float* __restrict__ sscaled,
                                                float* __restrict__ agg,
                                                float* __restrict__ sums) {
    __shared__ float ls[4][HID];
    __shared__ float lq[4][HID];
    int lane = threadIdx.x & 63, w = threadIdx.x >> 6;
    int wg = blockIdx.x * 4 + w;
    int nw = gridDim.x * 4;
    float s = 0.0f, q = 0.0f;
    for (int n = wg; n < N_NODES; n += nw) {
        int o0 = rowOff[n], o1 = rowOff[n + 1];
        float acc0 = 0.0f, acc1 = 0.0f, acc2 = 0.0f, acc3 = 0.0f;
        int e = o0;
        for (; e + 4 <= o1; e += 4) {
            int r0 = srow[e], r1 = srow[e + 1], r2 = srow[e + 2], r3 = srow[e + 3];
            acc0 += sscaled[(size_t)r0 * HID + lane];
            acc1 += sscaled[(size_t)r1 * HID + lane];
            acc2 += sscaled[(size_t)r2 * HID + lane];
            acc3 += sscaled[(size_t)r3 * HID + lane];
        }
        for (; e < o1; ++e) {
            int r = srow[e];
            acc0 += sscaled[(size_t)r * HID + lane];
        }
        float dv = dinv[n];
        size_t idx = (size_t)n * HID + lane;
        float a = agg[idx] + dv * ((acc0 + acc1) + (acc2 + acc3));
        agg[idx] = a;
        s += a;
        q = fmaf(a, a, q);
    }
    ls[w][lane] = s;
    lq[w][lane] = q;
    __syncthreads();
    if (threadIdx.x < HID) {
        float ts = ls[0][lane] + ls[1][lane] + ls[2][lane] + ls[3][lane];
        float tq = lq[0][lane] + lq[1][lane] + lq[2][lane] + lq[3][lane];
        atomicAdd(&sums[lane], ts);
        atomicAdd(&sums[HID + lane], tq);
    }
}

// ---------- output: h = hprev + relu(bn3(agg)); out = h @ Wo + bo ----------
__global__ __launch_bounds__(256) void k_out(const float* __restrict__ hprev,
                                             const float* __restrict__ agg,
                                             const float* __restrict__ sums,
                                             const float* __restrict__ gamma,
                                             const float* __restrict__ beta,
                                             const float* __restrict__ Wo,
                                             const float* __restrict__ bo,
                                             float* __restrict__ out) {
    __shared__ float wos[HID * 64];   // padded to 64 cols
    __shared__ float bos[64];
    for (int i = threadIdx.x; i < HID * 64; i += 256) wos[i] = 0.0f;
    __syncthreads();
    for (int i = threadIdx.x; i < HID * OUT_F; i += 256)
        wos[(i / OUT_F) * 64 + (i % OUT_F)] = Wo[i];
    if (threadIdx.x < 64) bos[threadIdx.x] = (threadIdx.x < OUT_F) ? bo[threadIdx.x] : 0.0f;
    __syncthreads();
    int wave = threadIdx.x >> 6, lane = threadIdx.x & 63;
    const float invN = 1.0f / (float)N_NODES;
    float mm = sums[lane] * invN;
    float vv = sums[HID + lane] * invN - mm * mm;
    float inv = rsqrtf(vv + BN_EPS);
    float g = gamma[lane], b = beta[lane];
    for (int n = blockIdx.x * 4 + wave; n < N_NODES; n += gridDim.x * 4) {
        size_t idx = (size_t)n * HID + lane;
        float a = agg[idx];
        float o = g * (a - mm) * inv + b;
        float h = hprev[idx] + fmaxf(o, 0.0f);
        float acc = bos[lane];
        #pragma unroll 16
        for (int k = 0; k < HID; ++k)
            acc = fmaf(__shfl(h, k, 64), wos[k * 64 + lane], acc);
        if (lane < OUT_F) out[(size_t)n * OUT_F + lane] = acc;
    }
}

extern "C" void kernel_launch(void* const* d_in, const int* in_sizes, int n_in,
                              void* d_out, int out_size, void* d_ws, size_t ws_size,
                              hipStream_t stream) {
    const float* x     = (const float*)d_in[0];
    const int*   ei    = (const int*)  d_in[1];   // [2, E]: row then col
    const float* Wi    = (const float*)d_in[2];
    const float* bi    = (const float*)d_in[3];
    const float* w1    = (const float*)d_in[4];
    const float* w2    = (const float*)d_in[5];
    const float* gamma = (const float*)d_in[6];
    const float* beta  = (const float*)d_in[7];
    const float* Wo    = (const float*)d_in[8];
    const float* bo    = (const float*)d_in[9];
    float* out = (float*)d_out;

    char* ws = (char*)d_ws;
    const size_t NH = (size_t)N_NODES * HID * sizeof(float);      // 25.6 MB
    size_t off = 0;
    auto alloc = [&](size_t bytes) { void* p = ws + off; off += (bytes + 255) & ~255UL; return p; };
    int*   degInt  = (int*)  alloc(N_NODES * sizeof(int));
    int*   tmpIncl = (int*)  alloc(N_NODES * sizeof(int));
    int*   blockSums = (int*)alloc(SCAN_BLOCKS * sizeof(int));
    int*   blockOff  = (int*)alloc(SCAN_BLOCKS * sizeof(int));
    int*   rowOff  = (int*)  alloc((N_NODES + 1) * sizeof(int));
    int*   cursor  = (int*)  alloc(N_NODES * sizeof(int));
    int*   srow    = (int*)  alloc(E_EDGES * sizeof(int));
    float* dinv    = (float*)alloc(N_NODES * sizeof(float));
    float* sscaled = (float*)alloc(NH);
    float* agg     = (float*)alloc(NH);
    float* h0      = (float*)alloc(NH);
    float* hprev   = (float*)alloc(NH);
    float* sums    = (float*)alloc(LAYERS * 128 * sizeof(float));
    (void)ws_size; (void)in_sizes; (void)n_in; (void)out_size;

    hipMemsetAsync(degInt, 0, N_NODES * sizeof(int), stream);
    hipMemsetAsync(sums, 0, LAYERS * 128 * sizeof(float), stream);

    k_deg_count<<<(E_EDGES + 255) / 256, 256, 0, stream>>>(ei + E_EDGES, degInt);
    k_scanA<<<SCAN_BLOCKS, 256, 0, stream>>>(degInt, tmpIncl, blockSums);
    k_scanB<<<1, 512, 0, stream>>>(blockSums, blockOff);
    k_scanC<<<SCAN_BLOCKS, 256, 0, stream>>>(degInt, tmpIncl, blockOff,
                                             rowOff, cursor, dinv);
    k_fill<<<(E_EDGES + 255) / 256, 256, 0, stream>>>(ei, cursor, srow);

    k_input<<<2048, 256, 0, stream>>>(x, Wi, bi, h0, hprev);

    for (int l = 0; l < LAYERS; ++l) {
        const float* sums_prev = (l > 0) ? (sums + (l - 1) * 128) : sums;
        const float* gm        = (l > 0) ? (gamma + (l - 1) * HID) : gamma;
        const float* bt        = (l > 0) ? (beta  + (l - 1) * HID) : beta;
        k_layerA<<<2048, 256, 0, stream>>>(hprev, h0, agg, sums_prev, gm, bt, (l > 0),
                                           w1 + (size_t)l * HID * HID,
                                           w2 + (size_t)l * HID * HID,
                                           dinv, sscaled);
        k_gather<<<2048, 256, 0, stream>>>(rowOff, srow, dinv, sscaled, agg,
                                           sums + l * 128);
    }

    k_out<<<2048, 256, 0, stream>>>(hprev, agg, sums + 3 * 128,
                                    gamma + 3 * HID, beta + 3 * HID, Wo, bo, out);
}

// Round 5
// 963.052 us; speedup vs baseline: 2.3033x; 1.6473x over previous
//
#include <hip/hip_runtime.h>

#define N_NODES 100000
#define E_EDGES 1000000
#define F_IN    128
#define HID     64
#define OUT_F   40
#define LAYERS  4
#define ALPHA   0.5f
#define BN_EPS  1e-5f

#define SCAN_BLOCKS ((N_NODES + 255) / 256)   // 391
#define TILE_BLOCKS ((N_NODES + 63) / 64)     // 1563

typedef __attribute__((ext_vector_type(8))) short short8;
typedef __attribute__((ext_vector_type(4))) float f32x4;

__device__ inline unsigned short f2bf(float f) {
    union { float f; unsigned u; } v; v.f = f;
    unsigned r = v.u + 0x7FFFu + ((v.u >> 16) & 1u);   // RNE
    return (unsigned short)(r >> 16);
}
__device__ inline float bf2f(unsigned short s) {
    union { unsigned u; float f; } v; v.u = ((unsigned)s) << 16;
    return v.f;
}

// ---------- CSR build ----------
__global__ __launch_bounds__(256) void k_deg_count(const int* __restrict__ col,
                                                   int* __restrict__ degInt) {
    int e = blockIdx.x * 256 + threadIdx.x;
    if (e < E_EDGES) atomicAdd(&degInt[col[e]], 1);
}

__global__ __launch_bounds__(256) void k_scanA(const int* __restrict__ degInt,
                                               int* __restrict__ tmpIncl,
                                               int* __restrict__ blockSums) {
    __shared__ int sm[256];
    int i = blockIdx.x * 256 + threadIdx.x;
    int v = (i < N_NODES) ? degInt[i] : 0;
    sm[threadIdx.x] = v;
    __syncthreads();
    for (int d = 1; d < 256; d <<= 1) {
        int t = (threadIdx.x >= d) ? sm[threadIdx.x - d] : 0;
        __syncthreads();
        sm[threadIdx.x] += t;
        __syncthreads();
    }
    if (i < N_NODES) tmpIncl[i] = sm[threadIdx.x];
    if (threadIdx.x == 255) blockSums[blockIdx.x] = sm[255];
}

__global__ __launch_bounds__(512) void k_scanB(int* __restrict__ blockSums,
                                               int* __restrict__ blockOff) {
    __shared__ int sm[512];
    int t = threadIdx.x;
    int v = (t < SCAN_BLOCKS) ? blockSums[t] : 0;
    sm[t] = v;
    __syncthreads();
    for (int d = 1; d < 512; d <<= 1) {
        int u = (t >= d) ? sm[t - d] : 0;
        __syncthreads();
        sm[t] += u;
        __syncthreads();
    }
    if (t < SCAN_BLOCKS) blockOff[t] = sm[t] - v;   // exclusive
}

__global__ __launch_bounds__(256) void k_scanC(const int* __restrict__ degInt,
                                               const int* __restrict__ tmpIncl,
                                               const int* __restrict__ blockOff,
                                               int* __restrict__ rowOff,
                                               int* __restrict__ cursor,
                                               float* __restrict__ dinv) {
    int i = blockIdx.x * 256 + threadIdx.x;
    if (i >= N_NODES) return;
    int d = degInt[i];
    int incl = tmpIncl[i] + blockOff[blockIdx.x];
    int excl = incl - d;
    rowOff[i] = excl;
    cursor[i] = excl;
    dinv[i] = rsqrtf((float)(d + 1));               // +1 self loop
    if (i == N_NODES - 1) rowOff[N_NODES] = incl;   // == E
}

__global__ __launch_bounds__(256) void k_fill(const int* __restrict__ ei,
                                              int* __restrict__ cursor,
                                              int* __restrict__ srow) {
    int e = blockIdx.x * 256 + threadIdx.x;
    if (e >= E_EDGES) return;
    int r = ei[e];
    int c = ei[E_EDGES + e];
    int pos = atomicAdd(&cursor[c], 1);
    srow[pos] = r;
}

// ---------- input layer: h = relu(x @ Wi + bi) -> h0 (f32 + bf16), hprev ----------
__global__ __launch_bounds__(256) void k_input(const float* __restrict__ x,
                                               const float* __restrict__ Wi,
                                               const float* __restrict__ bi,
                                               float* __restrict__ h0f,
                                               unsigned short* __restrict__ h0bf,
                                               float* __restrict__ hprev) {
    __shared__ float wis[F_IN * HID];
    for (int i = threadIdx.x; i < F_IN * HID; i += 256) wis[i] = Wi[i];
    __syncthreads();
    int wave = threadIdx.x >> 6, lane = threadIdx.x & 63;
    float bias = bi[lane];
    for (int n = blockIdx.x * 4 + wave; n < N_NODES; n += gridDim.x * 4) {
        float xlo = x[(size_t)n * F_IN + lane];
        float xhi = x[(size_t)n * F_IN + 64 + lane];
        float acc = bias;
        #pragma unroll 16
        for (int k = 0; k < 64; ++k)
            acc = fmaf(__shfl(xlo, k, 64), wis[k * HID + lane], acc);
        #pragma unroll 16
        for (int k = 0; k < 64; ++k)
            acc = fmaf(__shfl(xhi, k, 64), wis[(64 + k) * HID + lane], acc);
        float h = fmaxf(acc, 0.0f);
        int idx = n * HID + lane;
        h0f[idx]   = h;
        h0bf[idx]  = f2bf(h);
        hprev[idx] = h;
    }
}

// ---------- per-layer dense part, MFMA version. Block = 64 nodes.
// phase1: hp = hprev (+ relu(bn_prev(agg)) if apply_bn), write back hprev, stage LDS
// phase2: support = hp + hp@W1 ; ini = alpha*h0 + h0@W2
//         sscaled = dinv*support (bf16) ; agg = ini + dinv*sscaled ----------
__global__ __launch_bounds__(256) void k_layerA(float* __restrict__ hprev,
                                                const float* __restrict__ h0f,
                                                const unsigned short* __restrict__ h0bf,
                                                float* __restrict__ agg,
                                                const float* __restrict__ sums_prev,
                                                const float* __restrict__ gamma,
                                                const float* __restrict__ beta,
                                                int apply_bn,
                                                const float* __restrict__ w1g,
                                                const float* __restrict__ w2g,
                                                const float* __restrict__ dinv,
                                                unsigned short* __restrict__ sscaled) {
    __shared__ float hp_lds[64 * 68];                       // padded stride 68 (17.4 KB)
    __shared__ __align__(16) unsigned short wt1[64 * 72];   // W1^T bf16, stride 72 (9.2 KB)
    __shared__ __align__(16) unsigned short wt2[64 * 72];
    const int tid = threadIdx.x;
    const int n0 = blockIdx.x * 64;

    // stage weights transposed: wt[j][k] = W[k][j]
    for (int i = tid; i < HID * HID; i += 256) {
        int k = i >> 6, j = i & 63;
        wt1[j * 72 + k] = f2bf(w1g[i]);
        wt2[j * 72 + k] = f2bf(w2g[i]);
    }

    // phase 1: BN(prev)+relu+residual -> hp ; stage to LDS
    const int feat = tid & 63;
    const float invN = 1.0f / (float)N_NODES;
    float m = 0.f, inv = 0.f, gam = 0.f, bet = 0.f;
    if (apply_bn) {
        float mm = sums_prev[feat] * invN;
        float vv = sums_prev[HID + feat] * invN - mm * mm;
        m = mm; inv = rsqrtf(vv + BN_EPS);
        gam = gamma[feat]; bet = beta[feat];
    }
    const int nvalid = min(64, N_NODES - n0);
    for (int idx = tid; idx < 64 * HID; idx += 256) {
        int node = idx >> 6;
        float hp = 0.0f;
        if (node < nvalid) {
            int g = (n0 + node) * HID + feat;
            hp = hprev[g];
            if (apply_bn) {
                float a = agg[g];
                hp += fmaxf(gam * (a - m) * inv + bet, 0.0f);
                hprev[g] = hp;
            }
        }
        hp_lds[node * 68 + feat] = hp;
    }
    __syncthreads();

    // phase 2: MFMA
    const int lane = tid & 63, wid = tid >> 6;
    const int ml = lane & 15, gl = lane >> 4;
    const int r0 = wid * 16;                       // wave's 16-row stripe

    short8 A1[2], A2[2];
    #pragma unroll
    for (int ks = 0; ks < 2; ++ks) {
        const f32x4* p = (const f32x4*)&hp_lds[(r0 + ml) * 68 + ks * 32 + gl * 8];
        f32x4 x0 = p[0], x1 = p[1];
        short8 fr;
        fr[0] = f2bf(x0[0]); fr[1] = f2bf(x0[1]); fr[2] = f2bf(x0[2]); fr[3] = f2bf(x0[3]);
        fr[4] = f2bf(x1[0]); fr[5] = f2bf(x1[1]); fr[6] = f2bf(x1[2]); fr[7] = f2bf(x1[3]);
        A1[ks] = fr;
        A2[ks] = *(const short8*)&h0bf[(size_t)(n0 + r0 + ml) * HID + ks * 32 + gl * 8];
    }

    f32x4 acc1[4], acc2[4];
    #pragma unroll
    for (int ct = 0; ct < 4; ++ct) {
        short8 b10 = *(const short8*)&wt1[(ct * 16 + ml) * 72 + gl * 8];
        short8 b11 = *(const short8*)&wt1[(ct * 16 + ml) * 72 + 32 + gl * 8];
        short8 b20 = *(const short8*)&wt2[(ct * 16 + ml) * 72 + gl * 8];
        short8 b21 = *(const short8*)&wt2[(ct * 16 + ml) * 72 + 32 + gl * 8];
        f32x4 z = {0.f, 0.f, 0.f, 0.f};
        z = __builtin_amdgcn_mfma_f32_16x16x32_bf16(A1[0], b10, z, 0, 0, 0);
        z = __builtin_amdgcn_mfma_f32_16x16x32_bf16(A1[1], b11, z, 0, 0, 0);
        acc1[ct] = z;
        f32x4 y = {0.f, 0.f, 0.f, 0.f};
        y = __builtin_amdgcn_mfma_f32_16x16x32_bf16(A2[0], b20, y, 0, 0, 0);
        y = __builtin_amdgcn_mfma_f32_16x16x32_bf16(A2[1], b21, y, 0, 0, 0);
        acc2[ct] = y;
    }

    // epilogue: D row = gl*4 + reg, col = ct*16 + ml
    #pragma unroll
    for (int reg = 0; reg < 4; ++reg) {
        int i = gl * 4 + reg;
        int node = n0 + r0 + i;
        if (node < N_NODES) {
            float dv = dinv[node];
            #pragma unroll
            for (int ct = 0; ct < 4; ++ct) {
                int col = ct * 16 + ml;
                int gidx = node * HID + col;
                float hp = hp_lds[(r0 + i) * 68 + col];
                float hz = h0f[gidx];
                float s   = hp + acc1[ct][reg];
                float ini = ALPHA * hz + acc2[ct][reg];
                float ss  = dv * s;
                sscaled[gidx] = f2bf(ss);
                agg[gidx] = ini + dv * ss;
            }
        }
    }
}

// ---------- gather aggregation + fused BN statistics (bf16 rows) ----------
__global__ __launch_bounds__(256) void k_gather(const int* __restrict__ rowOff,
                                                const int* __restrict__ srow,
                                                const float* __restrict__ dinv,
                                                const unsigned short* __restrict__ sscaled,
                                                float* __restrict__ agg,
                                                float* __restrict__ sums) {
    __shared__ float ls[4][HID];
    __shared__ float lq[4][HID];
    int lane = threadIdx.x & 63, w = threadIdx.x >> 6;
    int wg = blockIdx.x * 4 + w;
    int nw = gridDim.x * 4;
    float s = 0.0f, q = 0.0f;
    for (int n = wg; n < N_NODES; n += nw) {
        int o0 = rowOff[n], o1 = rowOff[n + 1];
        float acc0 = 0.0f, acc1 = 0.0f, acc2 = 0.0f, acc3 = 0.0f;
        int e = o0;
        for (; e + 4 <= o1; e += 4) {
            int r0 = srow[e], r1 = srow[e + 1], r2 = srow[e + 2], r3 = srow[e + 3];
            acc0 += bf2f(sscaled[(size_t)r0 * HID + lane]);
            acc1 += bf2f(sscaled[(size_t)r1 * HID + lane]);
            acc2 += bf2f(sscaled[(size_t)r2 * HID + lane]);
            acc3 += bf2f(sscaled[(size_t)r3 * HID + lane]);
        }
        for (; e < o1; ++e) {
            int r = srow[e];
            acc0 += bf2f(sscaled[(size_t)r * HID + lane]);
        }
        float dv = dinv[n];
        size_t idx = (size_t)n * HID + lane;
        float a = agg[idx] + dv * ((acc0 + acc1) + (acc2 + acc3));
        agg[idx] = a;
        s += a;
        q = fmaf(a, a, q);
    }
    ls[w][lane] = s;
    lq[w][lane] = q;
    __syncthreads();
    if (threadIdx.x < HID) {
        float ts = ls[0][lane] + ls[1][lane] + ls[2][lane] + ls[3][lane];
        float tq = lq[0][lane] + lq[1][lane] + lq[2][lane] + lq[3][lane];
        atomicAdd(&sums[lane], ts);
        atomicAdd(&sums[HID + lane], tq);
    }
}

// ---------- output: h = hprev + relu(bn3(agg)); out = h @ Wo + bo ----------
__global__ __launch_bounds__(256) void k_out(const float* __restrict__ hprev,
                                             const float* __restrict__ agg,
                                             const float* __restrict__ sums,
                                             const float* __restrict__ gamma,
                                             const float* __restrict__ beta,
                                             const float* __restrict__ Wo,
                                             const float* __restrict__ bo,
                                             float* __restrict__ out) {
    __shared__ float wos[HID * 64];   // padded to 64 cols
    __shared__ float bos[64];
    for (int i = threadIdx.x; i < HID * 64; i += 256) wos[i] = 0.0f;
    __syncthreads();
    for (int i = threadIdx.x; i < HID * OUT_F; i += 256)
        wos[(i / OUT_F) * 64 + (i % OUT_F)] = Wo[i];
    if (threadIdx.x < 64) bos[threadIdx.x] = (threadIdx.x < OUT_F) ? bo[threadIdx.x] : 0.0f;
    __syncthreads();
    int wave = threadIdx.x >> 6, lane = threadIdx.x & 63;
    const float invN = 1.0f / (float)N_NODES;
    float mm = sums[lane] * invN;
    float vv = sums[HID + lane] * invN - mm * mm;
    float inv = rsqrtf(vv + BN_EPS);
    float g = gamma[lane], b = beta[lane];
    for (int n = blockIdx.x * 4 + wave; n < N_NODES; n += gridDim.x * 4) {
        size_t idx = (size_t)n * HID + lane;
        float a = agg[idx];
        float o = g * (a - mm) * inv + b;
        float h = hprev[idx] + fmaxf(o, 0.0f);
        float acc = bos[lane];
        #pragma unroll 16
        for (int k = 0; k < 64; ++k)
            acc = fmaf(__shfl(h, k, 64), wos[k * 64 + lane], acc);
        if (lane < OUT_F) out[(size_t)n * OUT_F + lane] = acc;
    }
}

extern "C" void kernel_launch(void* const* d_in, const int* in_sizes, int n_in,
                              void* d_out, int out_size, void* d_ws, size_t ws_size,
                              hipStream_t stream) {
    const float* x     = (const float*)d_in[0];
    const int*   ei    = (const int*)  d_in[1];   // [2, E]: row then col
    const float* Wi    = (const float*)d_in[2];
    const float* bi    = (const float*)d_in[3];
    const float* w1    = (const float*)d_in[4];
    const float* w2    = (const float*)d_in[5];
    const float* gamma = (const float*)d_in[6];
    const float* beta  = (const float*)d_in[7];
    const float* Wo    = (const float*)d_in[8];
    const float* bo    = (const float*)d_in[9];
    float* out = (float*)d_out;

    char* ws = (char*)d_ws;
    const size_t NH  = (size_t)N_NODES * HID * sizeof(float);          // 25.6 MB
    const size_t NHB = (size_t)N_NODES * HID * sizeof(unsigned short); // 12.8 MB
    size_t off = 0;
    auto alloc = [&](size_t bytes) { void* p = ws + off; off += (bytes + 255) & ~255UL; return p; };
    int*   degInt    = (int*)  alloc(N_NODES * sizeof(int));
    int*   tmpIncl   = (int*)  alloc(N_NODES * sizeof(int));
    int*   blockSums = (int*)  alloc(SCAN_BLOCKS * sizeof(int));
    int*   blockOff  = (int*)  alloc(SCAN_BLOCKS * sizeof(int));
    int*   rowOff    = (int*)  alloc((N_NODES + 1) * sizeof(int));
    int*   cursor    = (int*)  alloc(N_NODES * sizeof(int));
    int*   srow      = (int*)  alloc(E_EDGES * sizeof(int));
    float* dinv      = (float*)alloc(N_NODES * sizeof(float));
    unsigned short* sscaled = (unsigned short*)alloc(NHB);
    unsigned short* h0bf    = (unsigned short*)alloc(NHB);
    float* agg       = (float*)alloc(NH);
    float* h0f       = (float*)alloc(NH);
    float* hprev     = (float*)alloc(NH);
    float* sums      = (float*)alloc(LAYERS * 128 * sizeof(float));
    (void)ws_size; (void)in_sizes; (void)n_in; (void)out_size;

    hipMemsetAsync(degInt, 0, N_NODES * sizeof(int), stream);
    hipMemsetAsync(sums, 0, LAYERS * 128 * sizeof(float), stream);

    k_deg_count<<<(E_EDGES + 255) / 256, 256, 0, stream>>>(ei + E_EDGES, degInt);
    k_scanA<<<SCAN_BLOCKS, 256, 0, stream>>>(degInt, tmpIncl, blockSums);
    k_scanB<<<1, 512, 0, stream>>>(blockSums, blockOff);
    k_scanC<<<SCAN_BLOCKS, 256, 0, stream>>>(degInt, tmpIncl, blockOff,
                                             rowOff, cursor, dinv);
    k_fill<<<(E_EDGES + 255) / 256, 256, 0, stream>>>(ei, cursor, srow);

    k_input<<<2048, 256, 0, stream>>>(x, Wi, bi, h0f, h0bf, hprev);

    for (int l = 0; l < LAYERS; ++l) {
        const float* sums_prev = (l > 0) ? (sums + (l - 1) * 128) : sums;
        const float* gm        = (l > 0) ? (gamma + (l - 1) * HID) : gamma;
        const float* bt        = (l > 0) ? (beta  + (l - 1) * HID) : beta;
        k_layerA<<<TILE_BLOCKS, 256, 0, stream>>>(hprev, h0f, h0bf, agg,
                                                  sums_prev, gm, bt, (l > 0),
                                                  w1 + (size_t)l * HID * HID,
                                                  w2 + (size_t)l * HID * HID,
                                                  dinv, sscaled);
        k_gather<<<2048, 256, 0, stream>>>(rowOff, srow, dinv, sscaled, agg,
                                           sums + l * 128);
    }

    k_out<<<2048, 256, 0, stream>>>(hprev, agg, sums + 3 * 128,
                                    gamma + 3 * HID, beta + 3 * HID, Wo, bo, out);
}

// Round 8
// 748.625 us; speedup vs baseline: 2.9631x; 1.2864x over previous
//
#include <hip/hip_runtime.h>

#define N_NODES 100000
#define E_EDGES 1000000
#define F_IN    128
#define HID     64
#define OUT_F   40
#define LAYERS  4
#define ALPHA   0.5f
#define BN_EPS  1e-5f

#define SCAN_BLOCKS ((N_NODES + 255) / 256)   // 391
#define TILE_BLOCKS ((N_NODES + 63) / 64)     // 1563

typedef __attribute__((ext_vector_type(8))) short short8;
typedef __attribute__((ext_vector_type(4))) float f32x4;

__device__ inline unsigned short f2bf(float f) {
    union { float f; unsigned u; } v; v.f = f;
    unsigned r = v.u + 0x7FFFu + ((v.u >> 16) & 1u);   // RNE
    return (unsigned short)(r >> 16);
}
__device__ inline float bf2f(unsigned short s) {
    union { unsigned u; float f; } v; v.u = ((unsigned)s) << 16;
    return v.f;
}

// ---------- CSR build ----------
__global__ __launch_bounds__(256) void k_deg_count(const int* __restrict__ col,
                                                   int* __restrict__ degInt) {
    int e = blockIdx.x * 256 + threadIdx.x;
    if (e < E_EDGES) atomicAdd(&degInt[col[e]], 1);
}

__global__ __launch_bounds__(256) void k_scanA(const int* __restrict__ degInt,
                                               int* __restrict__ tmpIncl,
                                               int* __restrict__ blockSums) {
    __shared__ int sm[256];
    int i = blockIdx.x * 256 + threadIdx.x;
    int v = (i < N_NODES) ? degInt[i] : 0;
    sm[threadIdx.x] = v;
    __syncthreads();
    for (int d = 1; d < 256; d <<= 1) {
        int t = (threadIdx.x >= d) ? sm[threadIdx.x - d] : 0;
        __syncthreads();
        sm[threadIdx.x] += t;
        __syncthreads();
    }
    if (i < N_NODES) tmpIncl[i] = sm[threadIdx.x];
    if (threadIdx.x == 255) blockSums[blockIdx.x] = sm[255];
}

__global__ __launch_bounds__(512) void k_scanB(int* __restrict__ blockSums,
                                               int* __restrict__ blockOff) {
    __shared__ int sm[512];
    int t = threadIdx.x;
    int v = (t < SCAN_BLOCKS) ? blockSums[t] : 0;
    sm[t] = v;
    __syncthreads();
    for (int d = 1; d < 512; d <<= 1) {
        int u = (t >= d) ? sm[t - d] : 0;
        __syncthreads();
        sm[t] += u;
        __syncthreads();
    }
    if (t < SCAN_BLOCKS) blockOff[t] = sm[t] - v;   // exclusive
}

__global__ __launch_bounds__(256) void k_scanC(const int* __restrict__ degInt,
                                               const int* __restrict__ tmpIncl,
                                               const int* __restrict__ blockOff,
                                               int* __restrict__ rowOff,
                                               int* __restrict__ cursor,
                                               float* __restrict__ dinv) {
    int i = blockIdx.x * 256 + threadIdx.x;
    if (i >= N_NODES) return;
    int d = degInt[i];
    int incl = tmpIncl[i] + blockOff[blockIdx.x];
    int excl = incl - d;
    rowOff[i] = excl;
    cursor[i] = excl;
    dinv[i] = rsqrtf((float)(d + 1));               // +1 self loop
    if (i == N_NODES - 1) rowOff[N_NODES] = incl;   // == E
}

__global__ __launch_bounds__(256) void k_fill(const int* __restrict__ ei,
                                              int* __restrict__ cursor,
                                              int* __restrict__ srow) {
    int e = blockIdx.x * 256 + threadIdx.x;
    if (e >= E_EDGES) return;
    int r = ei[e];
    int c = ei[E_EDGES + e];
    int pos = atomicAdd(&cursor[c], 1);
    srow[pos] = r;
}

// ---------- input layer (MFMA): h = relu(x @ Wi + bi) -> h0bf (bf16), hprev (f32) ----------
__global__ __launch_bounds__(256) void k_input(const float* __restrict__ x,
                                               const float* __restrict__ Wi,
                                               const float* __restrict__ bi,
                                               unsigned short* __restrict__ h0bf,
                                               float* __restrict__ hprev) {
    __shared__ __align__(16) unsigned short xb[64 * 136];    // 17.4 KB
    __shared__ __align__(16) unsigned short wib[64 * 136];   // Wi^T bf16
    __shared__ float bis[64];
    const int tid = threadIdx.x;
    const int n0 = blockIdx.x * 64;
    const int nvalid = min(64, N_NODES - n0);

    if (tid < 64) bis[tid] = bi[tid];
    // stage Wi transposed: wib[j][k] = Wi[k*64+j]
    for (int i = tid; i < F_IN * HID; i += 256) {
        int k = i >> 6, j = i & 63;
        wib[j * 136 + k] = f2bf(Wi[i]);
    }
    // stage x tile rows (bf16)
    for (int i = tid; i < 64 * F_IN; i += 256) {
        int node = i >> 7, k = i & 127;
        float v = (node < nvalid) ? x[(size_t)(n0 + node) * F_IN + k] : 0.0f;
        xb[node * 136 + k] = f2bf(v);
    }
    __syncthreads();

    const int lane = tid & 63, wid = tid >> 6;
    const int ml = lane & 15, gl = lane >> 4;
    const int r0 = wid * 16;

    short8 A[4];
    #pragma unroll
    for (int ks = 0; ks < 4; ++ks)
        A[ks] = *(const short8*)&xb[(r0 + ml) * 136 + ks * 32 + gl * 8];

    #pragma unroll
    for (int ct = 0; ct < 4; ++ct) {
        f32x4 z = {0.f, 0.f, 0.f, 0.f};
        #pragma unroll
        for (int ks = 0; ks < 4; ++ks) {
            short8 b = *(const short8*)&wib[(ct * 16 + ml) * 136 + ks * 32 + gl * 8];
            z = __builtin_amdgcn_mfma_f32_16x16x32_bf16(A[ks], b, z, 0, 0, 0);
        }
        #pragma unroll
        for (int reg = 0; reg < 4; ++reg) {
            int node = n0 + r0 + gl * 4 + reg;
            if (node < N_NODES) {
                int col = ct * 16 + ml;
                float h = fmaxf(z[reg] + bis[col], 0.0f);
                int gidx = node * HID + col;
                h0bf[gidx]  = f2bf(h);
                hprev[gidx] = h;
            }
        }
    }
}

// ---------- per-layer dense part, MFMA. Block = 64 nodes. ----------
__global__ __launch_bounds__(256) void k_layerA(float* __restrict__ hprev,
                                                const unsigned short* __restrict__ h0bf,
                                                float* __restrict__ agg,
                                                const float* __restrict__ sums_prev,
                                                const float* __restrict__ gamma,
                                                const float* __restrict__ beta,
                                                int apply_bn,
                                                const float* __restrict__ w1g,
                                                const float* __restrict__ w2g,
                                                const float* __restrict__ dinv,
                                                unsigned short* __restrict__ sscaled) {
    __shared__ float hp_lds[64 * 68];                       // stride 68 (17.4 KB)
    __shared__ __align__(16) unsigned short wt1[64 * 72];   // W1^T bf16 (9.2 KB)
    __shared__ __align__(16) unsigned short wt2[64 * 72];
    const int tid = threadIdx.x;
    const int n0 = blockIdx.x * 64;

    for (int i = tid; i < HID * HID; i += 256) {
        int k = i >> 6, j = i & 63;
        wt1[j * 72 + k] = f2bf(w1g[i]);
        wt2[j * 72 + k] = f2bf(w2g[i]);
    }

    const int feat = tid & 63;
    const float invN = 1.0f / (float)N_NODES;
    float m = 0.f, inv = 0.f, gam = 0.f, bet = 0.f;
    if (apply_bn) {
        float mm = sums_prev[feat] * invN;
        float vv = sums_prev[HID + feat] * invN - mm * mm;
        m = mm; inv = rsqrtf(vv + BN_EPS);
        gam = gamma[feat]; bet = beta[feat];
    }
    const int nvalid = min(64, N_NODES - n0);
    for (int idx = tid; idx < 64 * HID; idx += 256) {
        int node = idx >> 6;
        float hp = 0.0f;
        if (node < nvalid) {
            int g = (n0 + node) * HID + feat;
            hp = hprev[g];
            if (apply_bn) {
                float a = agg[g];
                hp += fmaxf(gam * (a - m) * inv + bet, 0.0f);
                hprev[g] = hp;
            }
        }
        hp_lds[node * 68 + feat] = hp;
    }
    __syncthreads();

    const int lane = tid & 63, wid = tid >> 6;
    const int ml = lane & 15, gl = lane >> 4;
    const int r0 = wid * 16;

    short8 A1[2], A2[2];
    #pragma unroll
    for (int ks = 0; ks < 2; ++ks) {
        const f32x4* p = (const f32x4*)&hp_lds[(r0 + ml) * 68 + ks * 32 + gl * 8];
        f32x4 x0 = p[0], x1 = p[1];
        short8 fr;
        fr[0] = f2bf(x0[0]); fr[1] = f2bf(x0[1]); fr[2] = f2bf(x0[2]); fr[3] = f2bf(x0[3]);
        fr[4] = f2bf(x1[0]); fr[5] = f2bf(x1[1]); fr[6] = f2bf(x1[2]); fr[7] = f2bf(x1[3]);
        A1[ks] = fr;
        A2[ks] = *(const short8*)&h0bf[(size_t)(n0 + r0 + ml) * HID + ks * 32 + gl * 8];
    }

    f32x4 acc1[4], acc2[4];
    #pragma unroll
    for (int ct = 0; ct < 4; ++ct) {
        short8 b10 = *(const short8*)&wt1[(ct * 16 + ml) * 72 + gl * 8];
        short8 b11 = *(const short8*)&wt1[(ct * 16 + ml) * 72 + 32 + gl * 8];
        short8 b20 = *(const short8*)&wt2[(ct * 16 + ml) * 72 + gl * 8];
        short8 b21 = *(const short8*)&wt2[(ct * 16 + ml) * 72 + 32 + gl * 8];
        f32x4 z = {0.f, 0.f, 0.f, 0.f};
        z = __builtin_amdgcn_mfma_f32_16x16x32_bf16(A1[0], b10, z, 0, 0, 0);
        z = __builtin_amdgcn_mfma_f32_16x16x32_bf16(A1[1], b11, z, 0, 0, 0);
        acc1[ct] = z;
        f32x4 y = {0.f, 0.f, 0.f, 0.f};
        y = __builtin_amdgcn_mfma_f32_16x16x32_bf16(A2[0], b20, y, 0, 0, 0);
        y = __builtin_amdgcn_mfma_f32_16x16x32_bf16(A2[1], b21, y, 0, 0, 0);
        acc2[ct] = y;
    }

    #pragma unroll
    for (int reg = 0; reg < 4; ++reg) {
        int i = gl * 4 + reg;
        int node = n0 + r0 + i;
        if (node < N_NODES) {
            float dv = dinv[node];
            #pragma unroll
            for (int ct = 0; ct < 4; ++ct) {
                int col = ct * 16 + ml;
                int gidx = node * HID + col;
                float hp = hp_lds[(r0 + i) * 68 + col];
                float hz = bf2f(h0bf[gidx]);
                float s   = hp + acc1[ct][reg];
                float ini = ALPHA * hz + acc2[ct][reg];
                float ss  = dv * s;
                sscaled[gidx] = f2bf(ss);
                agg[gidx] = ini + dv * ss;
            }
        }
    }
}

// ---------- gather aggregation + fused BN statistics (bf16 rows) ----------
__global__ __launch_bounds__(256) void k_gather(const int* __restrict__ rowOff,
                                                const int* __restrict__ srow,
                                                const float* __restrict__ dinv,
                                                const unsigned short* __restrict__ sscaled,
                                                float* __restrict__ agg,
                                                float* __restrict__ sums) {
    __shared__ float ls[4][HID];
    __shared__ float lq[4][HID];
    int lane = threadIdx.x & 63, w = threadIdx.x >> 6;
    int wg = blockIdx.x * 4 + w;
    int nw = gridDim.x * 4;
    float s = 0.0f, q = 0.0f;
    for (int n = wg; n < N_NODES; n += nw) {
        int o0 = rowOff[n], o1 = rowOff[n + 1];
        float acc0 = 0.0f, acc1 = 0.0f, acc2 = 0.0f, acc3 = 0.0f;
        int e = o0;
        for (; e + 4 <= o1; e += 4) {
            int r0 = srow[e], r1 = srow[e + 1], r2 = srow[e + 2], r3 = srow[e + 3];
            acc0 += bf2f(sscaled[(size_t)r0 * HID + lane]);
            acc1 += bf2f(sscaled[(size_t)r1 * HID + lane]);
            acc2 += bf2f(sscaled[(size_t)r2 * HID + lane]);
            acc3 += bf2f(sscaled[(size_t)r3 * HID + lane]);
        }
        for (; e < o1; ++e) {
            int r = srow[e];
            acc0 += bf2f(sscaled[(size_t)r * HID + lane]);
        }
        float dv = dinv[n];
        size_t idx = (size_t)n * HID + lane;
        float a = agg[idx] + dv * ((acc0 + acc1) + (acc2 + acc3));
        agg[idx] = a;
        s += a;
        q = fmaf(a, a, q);
    }
    ls[w][lane] = s;
    lq[w][lane] = q;
    __syncthreads();
    if (threadIdx.x < HID) {
        float ts = ls[0][lane] + ls[1][lane] + ls[2][lane] + ls[3][lane];
        float tq = lq[0][lane] + lq[1][lane] + lq[2][lane] + lq[3][lane];
        atomicAdd(&sums[lane], ts);
        atomicAdd(&sums[HID + lane], tq);
    }
}

// ---------- output (MFMA): h = hprev + relu(bn3(agg)); out = h @ Wo + bo ----------
__global__ __launch_bounds__(256) void k_out(const float* __restrict__ hprev,
                                             const float* __restrict__ agg,
                                             const float* __restrict__ sums,
                                             const float* __restrict__ gamma,
                                             const float* __restrict__ beta,
                                             const float* __restrict__ Wo,
                                             const float* __restrict__ bo,
                                             float* __restrict__ out) {
    __shared__ __align__(16) unsigned short hb[64 * 72];    // 9.2 KB
    __shared__ __align__(16) unsigned short wot[48 * 72];   // Wo^T bf16, cols padded to 48
    __shared__ float bos[48];
    const int tid = threadIdx.x;
    const int n0 = blockIdx.x * 64;
    const int nvalid = min(64, N_NODES - n0);

    for (int i = tid; i < 48 * 72; i += 256) wot[i] = 0;
    if (tid < 48) bos[tid] = (tid < OUT_F) ? bo[tid] : 0.0f;
    __syncthreads();
    for (int i = tid; i < HID * OUT_F; i += 256) {
        int k = i / OUT_F, j = i % OUT_F;       // Wo[k][j]
        wot[j * 72 + k] = f2bf(Wo[i]);
    }

    const int feat = tid & 63;
    const float invN = 1.0f / (float)N_NODES;
    float mm = sums[feat] * invN;
    float vv = sums[HID + feat] * invN - mm * mm;
    float inv = rsqrtf(vv + BN_EPS);
    float g = gamma[feat], b = beta[feat];
    for (int idx = tid; idx < 64 * HID; idx += 256) {
        int node = idx >> 6;
        float h = 0.0f;
        if (node < nvalid) {
            int gi = (n0 + node) * HID + feat;
            float a = agg[gi];
            h = hprev[gi] + fmaxf(g * (a - mm) * inv + b, 0.0f);
        }
        hb[node * 72 + feat] = f2bf(h);
    }
    __syncthreads();

    const int lane = tid & 63, wid = tid >> 6;
    const int ml = lane & 15, gl = lane >> 4;
    const int r0 = wid * 16;

    short8 A0 = *(const short8*)&hb[(r0 + ml) * 72 + gl * 8];
    short8 A1 = *(const short8*)&hb[(r0 + ml) * 72 + 32 + gl * 8];

    #pragma unroll
    for (int ct = 0; ct < 3; ++ct) {
        short8 b0 = *(const short8*)&wot[(ct * 16 + ml) * 72 + gl * 8];
        short8 b1 = *(const short8*)&wot[(ct * 16 + ml) * 72 + 32 + gl * 8];
        f32x4 z = {0.f, 0.f, 0.f, 0.f};
        z = __builtin_amdgcn_mfma_f32_16x16x32_bf16(A0, b0, z, 0, 0, 0);
        z = __builtin_amdgcn_mfma_f32_16x16x32_bf16(A1, b1, z, 0, 0, 0);
        int col = ct * 16 + ml;
        #pragma unroll
        for (int reg = 0; reg < 4; ++reg) {
            int node = n0 + r0 + gl * 4 + reg;
            if (node < N_NODES && col < OUT_F)
                out[(size_t)node * OUT_F + col] = z[reg] + bos[col];
        }
    }
}

extern "C" void kernel_launch(void* const* d_in, const int* in_sizes, int n_in,
                              void* d_out, int out_size, void* d_ws, size_t ws_size,
                              hipStream_t stream) {
    const float* x     = (const float*)d_in[0];
    const int*   ei    = (const int*)  d_in[1];   // [2, E]: row then col
    const float* Wi    = (const float*)d_in[2];
    const float* bi    = (const float*)d_in[3];
    const float* w1    = (const float*)d_in[4];
    const float* w2    = (const float*)d_in[5];
    const float* gamma = (const float*)d_in[6];
    const float* beta  = (const float*)d_in[7];
    const float* Wo    = (const float*)d_in[8];
    const float* bo    = (const float*)d_in[9];
    float* out = (float*)d_out;

    char* ws = (char*)d_ws;
    const size_t NH  = (size_t)N_NODES * HID * sizeof(float);          // 25.6 MB
    const size_t NHB = (size_t)N_NODES * HID * sizeof(unsigned short); // 12.8 MB
    size_t off = 0;
    auto alloc = [&](size_t bytes) { void* p = ws + off; off += (bytes + 255) & ~255UL; return p; };
    int*   degInt    = (int*)  alloc(N_NODES * sizeof(int));
    int*   tmpIncl   = (int*)  alloc(N_NODES * sizeof(int));
    int*   blockSums = (int*)  alloc(SCAN_BLOCKS * sizeof(int));
    int*   blockOff  = (int*)  alloc(SCAN_BLOCKS * sizeof(int));
    int*   rowOff    = (int*)  alloc((N_NODES + 1) * sizeof(int));
    int*   cursor    = (int*)  alloc(N_NODES * sizeof(int));
    int*   srow      = (int*)  alloc(E_EDGES * sizeof(int));
    float* dinv      = (float*)alloc(N_NODES * sizeof(float));
    unsigned short* sscaled = (unsigned short*)alloc(NHB);
    unsigned short* h0bf    = (unsigned short*)alloc(NHB);
    float* agg       = (float*)alloc(NH);
    float* hprev     = (float*)alloc(NH);
    float* sums      = (float*)alloc(LAYERS * 128 * sizeof(float));
    (void)ws_size; (void)in_sizes; (void)n_in; (void)out_size;

    hipMemsetAsync(degInt, 0, N_NODES * sizeof(int), stream);
    hipMemsetAsync(sums, 0, LAYERS * 128 * sizeof(float), stream);

    k_deg_count<<<(E_EDGES + 255) / 256, 256, 0, stream>>>(ei + E_EDGES, degInt);
    k_scanA<<<SCAN_BLOCKS, 256, 0, stream>>>(degInt, tmpIncl, blockSums);
    k_scanB<<<1, 512, 0, stream>>>(blockSums, blockOff);
    k_scanC<<<SCAN_BLOCKS, 256, 0, stream>>>(degInt, tmpIncl, blockOff,
                                             rowOff, cursor, dinv);
    k_fill<<<(E_EDGES + 255) / 256, 256, 0, stream>>>(ei, cursor, srow);

    k_input<<<TILE_BLOCKS, 256, 0, stream>>>(x, Wi, bi, h0bf, hprev);

    for (int l = 0; l < LAYERS; ++l) {
        const float* sums_prev = (l > 0) ? (sums + (l - 1) * 128) : sums;
        const float* gm        = (l > 0) ? (gamma + (l - 1) * HID) : gamma;
        const float* bt        = (l > 0) ? (beta  + (l - 1) * HID) : beta;
        k_layerA<<<TILE_BLOCKS, 256, 0, stream>>>(hprev, h0bf, agg,
                                                  sums_prev, gm, bt, (l > 0),
                                                  w1 + (size_t)l * HID * HID,
                                                  w2 + (size_t)l * HID * HID,
                                                  dinv, sscaled);
        k_gather<<<2048, 256, 0, stream>>>(rowOff, srow, dinv, sscaled, agg,
                                           sums + l * 128);
    }

    k_out<<<TILE_BLOCKS, 256, 0, stream>>>(hprev, agg, sums + 3 * 128,
                                           gamma + 3 * HID, beta + 3 * HID, Wo, bo, out);
}

// Round 10
// 717.663 us; speedup vs baseline: 3.0909x; 1.0431x over previous
//
#include <hip/hip_runtime.h>

#define N_NODES 100000
#define E_EDGES 1000000
#define F_IN    128
#define HID     64
#define OUT_F   40
#define LAYERS  4
#define ALPHA   0.5f
#define BN_EPS  1e-5f

#define SCAN_BLOCKS ((N_NODES + 255) / 256)   // 391
#define TILE_BLOCKS ((N_NODES + 63) / 64)     // 1563

typedef __attribute__((ext_vector_type(8))) short short8;
typedef __attribute__((ext_vector_type(4))) float f32x4;
typedef __attribute__((ext_vector_type(4))) unsigned short ushort4v;

__device__ inline unsigned short f2bf(float f) {
    union { float f; unsigned u; } v; v.f = f;
    unsigned r = v.u + 0x7FFFu + ((v.u >> 16) & 1u);   // RNE
    return (unsigned short)(r >> 16);
}
__device__ inline float bf2f(unsigned short s) {
    union { unsigned u; float f; } v; v.u = ((unsigned)s) << 16;
    return v.f;
}

// ---------- CSR build ----------
__global__ __launch_bounds__(256) void k_deg_count(const int* __restrict__ col,
                                                   int* __restrict__ degInt) {
    int e = blockIdx.x * 256 + threadIdx.x;
    if (e < E_EDGES) atomicAdd(&degInt[col[e]], 1);
}

__global__ __launch_bounds__(256) void k_scanA(const int* __restrict__ degInt,
                                               int* __restrict__ tmpIncl,
                                               int* __restrict__ blockSums) {
    __shared__ int sm[256];
    int i = blockIdx.x * 256 + threadIdx.x;
    int v = (i < N_NODES) ? degInt[i] : 0;
    sm[threadIdx.x] = v;
    __syncthreads();
    for (int d = 1; d < 256; d <<= 1) {
        int t = (threadIdx.x >= d) ? sm[threadIdx.x - d] : 0;
        __syncthreads();
        sm[threadIdx.x] += t;
        __syncthreads();
    }
    if (i < N_NODES) tmpIncl[i] = sm[threadIdx.x];
    if (threadIdx.x == 255) blockSums[blockIdx.x] = sm[255];
}

__global__ __launch_bounds__(512) void k_scanB(int* __restrict__ blockSums,
                                               int* __restrict__ blockOff) {
    __shared__ int sm[512];
    int t = threadIdx.x;
    int v = (t < SCAN_BLOCKS) ? blockSums[t] : 0;
    sm[t] = v;
    __syncthreads();
    for (int d = 1; d < 512; d <<= 1) {
        int u = (t >= d) ? sm[t - d] : 0;
        __syncthreads();
        sm[t] += u;
        __syncthreads();
    }
    if (t < SCAN_BLOCKS) blockOff[t] = sm[t] - v;   // exclusive
}

__global__ __launch_bounds__(256) void k_scanC(const int* __restrict__ degInt,
                                               const int* __restrict__ tmpIncl,
                                               const int* __restrict__ blockOff,
                                               int* __restrict__ rowOff,
                                               int* __restrict__ cursor,
                                               float* __restrict__ dinv) {
    int i = blockIdx.x * 256 + threadIdx.x;
    if (i >= N_NODES) return;
    int d = degInt[i];
    int incl = tmpIncl[i] + blockOff[blockIdx.x];
    int excl = incl - d;
    rowOff[i] = excl;
    cursor[i] = excl;
    dinv[i] = rsqrtf((float)(d + 1));               // +1 self loop
    if (i == N_NODES - 1) rowOff[N_NODES] = incl;   // == E
}

__global__ __launch_bounds__(256) void k_fill(const int* __restrict__ ei,
                                              int* __restrict__ cursor,
                                              int* __restrict__ srow) {
    int e = blockIdx.x * 256 + threadIdx.x;
    if (e >= E_EDGES) return;
    int r = ei[e];
    int c = ei[E_EDGES + e];
    int pos = atomicAdd(&cursor[c], 1);
    srow[pos] = r;
}

// ---------- input layer (MFMA): h = relu(x @ Wi + bi) -> h0bf (bf16), hprev (f32) ----------
__global__ __launch_bounds__(256) void k_input(const float* __restrict__ x,
                                               const float* __restrict__ Wi,
                                               const float* __restrict__ bi,
                                               unsigned short* __restrict__ h0bf,
                                               float* __restrict__ hprev) {
    __shared__ __align__(16) unsigned short xb[64 * 136];    // 17.4 KB
    __shared__ __align__(16) unsigned short wib[64 * 136];   // Wi^T bf16
    __shared__ float bis[64];
    const int tid = threadIdx.x;
    const int n0 = blockIdx.x * 64;
    const int nvalid = min(64, N_NODES - n0);

    if (tid < 64) bis[tid] = bi[tid];
    // stage Wi transposed: wib[j][k] = Wi[k*64+j]
    for (int i = tid; i < F_IN * HID; i += 256) {
        int k = i >> 6, j = i & 63;
        wib[j * 136 + k] = f2bf(Wi[i]);
    }
    // stage x tile rows (bf16)
    for (int i = tid; i < 64 * F_IN; i += 256) {
        int node = i >> 7, k = i & 127;
        float v = (node < nvalid) ? x[(size_t)(n0 + node) * F_IN + k] : 0.0f;
        xb[node * 136 + k] = f2bf(v);
    }
    __syncthreads();

    const int lane = tid & 63, wid = tid >> 6;
    const int ml = lane & 15, gl = lane >> 4;
    const int r0 = wid * 16;

    short8 A[4];
    #pragma unroll
    for (int ks = 0; ks < 4; ++ks)
        A[ks] = *(const short8*)&xb[(r0 + ml) * 136 + ks * 32 + gl * 8];

    #pragma unroll
    for (int ct = 0; ct < 4; ++ct) {
        f32x4 z = {0.f, 0.f, 0.f, 0.f};
        #pragma unroll
        for (int ks = 0; ks < 4; ++ks) {
            short8 b = *(const short8*)&wib[(ct * 16 + ml) * 136 + ks * 32 + gl * 8];
            z = __builtin_amdgcn_mfma_f32_16x16x32_bf16(A[ks], b, z, 0, 0, 0);
        }
        #pragma unroll
        for (int reg = 0; reg < 4; ++reg) {
            int node = n0 + r0 + gl * 4 + reg;
            if (node < N_NODES) {
                int col = ct * 16 + ml;
                float h = fmaxf(z[reg] + bis[col], 0.0f);
                int gidx = node * HID + col;
                h0bf[gidx]  = f2bf(h);
                hprev[gidx] = h;
            }
        }
    }
}

// ---------- per-layer dense part, MFMA. Block = 64 nodes. ----------
__global__ __launch_bounds__(256) void k_layerA(float* __restrict__ hprev,
                                                const unsigned short* __restrict__ h0bf,
                                                float* __restrict__ agg,
                                                const float* __restrict__ sums_prev,
                                                const float* __restrict__ gamma,
                                                const float* __restrict__ beta,
                                                int apply_bn,
                                                const float* __restrict__ w1g,
                                                const float* __restrict__ w2g,
                                                const float* __restrict__ dinv,
                                                unsigned short* __restrict__ sscaled) {
    __shared__ float hp_lds[64 * 68];                       // stride 68 (17.4 KB)
    __shared__ __align__(16) unsigned short wt1[64 * 72];   // W1^T bf16 (9.2 KB)
    __shared__ __align__(16) unsigned short wt2[64 * 72];
    const int tid = threadIdx.x;
    const int n0 = blockIdx.x * 64;

    for (int i = tid; i < HID * HID; i += 256) {
        int k = i >> 6, j = i & 63;
        wt1[j * 72 + k] = f2bf(w1g[i]);
        wt2[j * 72 + k] = f2bf(w2g[i]);
    }

    const int feat = tid & 63;
    const float invN = 1.0f / (float)N_NODES;
    float m = 0.f, inv = 0.f, gam = 0.f, bet = 0.f;
    if (apply_bn) {
        float mm = sums_prev[feat] * invN;
        float vv = sums_prev[HID + feat] * invN - mm * mm;
        m = mm; inv = rsqrtf(vv + BN_EPS);
        gam = gamma[feat]; bet = beta[feat];
    }
    const int nvalid = min(64, N_NODES - n0);
    for (int idx = tid; idx < 64 * HID; idx += 256) {
        int node = idx >> 6;
        float hp = 0.0f;
        if (node < nvalid) {
            int g = (n0 + node) * HID + feat;
            hp = hprev[g];
            if (apply_bn) {
                float a = agg[g];
                hp += fmaxf(gam * (a - m) * inv + bet, 0.0f);
                hprev[g] = hp;
            }
        }
        hp_lds[node * 68 + feat] = hp;
    }
    __syncthreads();

    const int lane = tid & 63, wid = tid >> 6;
    const int ml = lane & 15, gl = lane >> 4;
    const int r0 = wid * 16;

    short8 A1[2], A2[2];
    #pragma unroll
    for (int ks = 0; ks < 2; ++ks) {
        const f32x4* p = (const f32x4*)&hp_lds[(r0 + ml) * 68 + ks * 32 + gl * 8];
        f32x4 x0 = p[0], x1 = p[1];
        short8 fr;
        fr[0] = f2bf(x0[0]); fr[1] = f2bf(x0[1]); fr[2] = f2bf(x0[2]); fr[3] = f2bf(x0[3]);
        fr[4] = f2bf(x1[0]); fr[5] = f2bf(x1[1]); fr[6] = f2bf(x1[2]); fr[7] = f2bf(x1[3]);
        A1[ks] = fr;
        A2[ks] = *(const short8*)&h0bf[(size_t)(n0 + r0 + ml) * HID + ks * 32 + gl * 8];
    }

    f32x4 acc1[4], acc2[4];
    #pragma unroll
    for (int ct = 0; ct < 4; ++ct) {
        short8 b10 = *(const short8*)&wt1[(ct * 16 + ml) * 72 + gl * 8];
        short8 b11 = *(const short8*)&wt1[(ct * 16 + ml) * 72 + 32 + gl * 8];
        short8 b20 = *(const short8*)&wt2[(ct * 16 + ml) * 72 + gl * 8];
        short8 b21 = *(const short8*)&wt2[(ct * 16 + ml) * 72 + 32 + gl * 8];
        f32x4 z = {0.f, 0.f, 0.f, 0.f};
        z = __builtin_amdgcn_mfma_f32_16x16x32_bf16(A1[0], b10, z, 0, 0, 0);
        z = __builtin_amdgcn_mfma_f32_16x16x32_bf16(A1[1], b11, z, 0, 0, 0);
        acc1[ct] = z;
        f32x4 y = {0.f, 0.f, 0.f, 0.f};
        y = __builtin_amdgcn_mfma_f32_16x16x32_bf16(A2[0], b20, y, 0, 0, 0);
        y = __builtin_amdgcn_mfma_f32_16x16x32_bf16(A2[1], b21, y, 0, 0, 0);
        acc2[ct] = y;
    }

    #pragma unroll
    for (int reg = 0; reg < 4; ++reg) {
        int i = gl * 4 + reg;
        int node = n0 + r0 + i;
        if (node < N_NODES) {
            float dv = dinv[node];
            #pragma unroll
            for (int ct = 0; ct < 4; ++ct) {
                int col = ct * 16 + ml;
                int gidx = node * HID + col;
                float hp = hp_lds[(r0 + i) * 68 + col];
                float hz = bf2f(h0bf[gidx]);
                float s   = hp + acc1[ct][reg];
                float ini = ALPHA * hz + acc2[ct][reg];
                float ss  = dv * s;
                sscaled[gidx] = f2bf(ss);
                agg[gidx] = ini + dv * ss;
            }
        }
    }
}

// ---------- gather aggregation + fused BN statistics (wide loads) ----------
// 16 lanes per edge row (ushort4 = 8B/lane); wave covers 4 edges per load.
__global__ __launch_bounds__(256) void k_gather(const int* __restrict__ rowOff,
                                                const int* __restrict__ srow,
                                                const float* __restrict__ dinv,
                                                const unsigned short* __restrict__ sscaled,
                                                float* __restrict__ agg,
                                                float* __restrict__ sums) {
    __shared__ float ls[4][HID];
    __shared__ float lq[4][HID];
    const int tid = threadIdx.x;
    const int lane = tid & 63, w = tid >> 6;
    const int ml = lane & 15, gl = lane >> 4;     // feature-quarter, edge-group
    int wg = blockIdx.x * 4 + w;
    int nw = gridDim.x * 4;
    f32x4 s4 = {0.f, 0.f, 0.f, 0.f}, q4 = {0.f, 0.f, 0.f, 0.f};

    for (int n = wg; n < N_NODES; n += nw) {
        int o0 = rowOff[n], o1 = rowOff[n + 1];
        f32x4 accA = {0.f, 0.f, 0.f, 0.f};
        f32x4 accB = {0.f, 0.f, 0.f, 0.f};
        int e = o0;
        for (; e + 8 <= o1; e += 8) {               // 8 edges in flight per wave
            int rA = srow[e + gl];
            int rB = srow[e + 4 + gl];
            ushort4v a = *(const ushort4v*)&sscaled[(size_t)rA * HID + ml * 4];
            ushort4v b = *(const ushort4v*)&sscaled[(size_t)rB * HID + ml * 4];
            accA[0] += bf2f(a[0]); accA[1] += bf2f(a[1]);
            accA[2] += bf2f(a[2]); accA[3] += bf2f(a[3]);
            accB[0] += bf2f(b[0]); accB[1] += bf2f(b[1]);
            accB[2] += bf2f(b[2]); accB[3] += bf2f(b[3]);
        }
        for (; e < o1; e += 4) {                    // predicated tail, 4 edges/iter
            int idx = e + gl;
            if (idx < o1) {
                int r = srow[idx];
                ushort4v a = *(const ushort4v*)&sscaled[(size_t)r * HID + ml * 4];
                accA[0] += bf2f(a[0]); accA[1] += bf2f(a[1]);
                accA[2] += bf2f(a[2]); accA[3] += bf2f(a[3]);
            }
        }
        f32x4 acc = accA + accB;
        #pragma unroll
        for (int j = 0; j < 4; ++j) {               // reduce over 4 edge-groups
            float v = acc[j];
            v += __shfl_xor(v, 16, 64);
            v += __shfl_xor(v, 32, 64);
            acc[j] = v;
        }
        float dv = dinv[n];
        if (gl == 0) {                              // coalesced float4 RMW + stats
            f32x4* ap = (f32x4*)&agg[(size_t)n * HID + ml * 4];
            f32x4 a = *ap;
            #pragma unroll
            for (int j = 0; j < 4; ++j) a[j] += dv * acc[j];
            *ap = a;
            #pragma unroll
            for (int j = 0; j < 4; ++j) {
                s4[j] += a[j];
                q4[j] = fmaf(a[j], a[j], q4[j]);
            }
        }
    }

    if (gl == 0) {
        #pragma unroll
        for (int j = 0; j < 4; ++j) {
            ls[w][ml * 4 + j] = s4[j];
            lq[w][ml * 4 + j] = q4[j];
        }
    }
    __syncthreads();
    if (tid < HID) {
        float ts = ls[0][tid] + ls[1][tid] + ls[2][tid] + ls[3][tid];
        float tq = lq[0][tid] + lq[1][tid] + lq[2][tid] + lq[3][tid];
        atomicAdd(&sums[tid], ts);
        atomicAdd(&sums[HID + tid], tq);
    }
}

// ---------- output (MFMA): h = hprev + relu(bn3(agg)); out = h @ Wo + bo ----------
__global__ __launch_bounds__(256) void k_out(const float* __restrict__ hprev,
                                             const float* __restrict__ agg,
                                             const float* __restrict__ sums,
                                             const float* __restrict__ gamma,
                                             const float* __restrict__ beta,
                                             const float* __restrict__ Wo,
                                             const float* __restrict__ bo,
                                             float* __restrict__ out) {
    __shared__ __align__(16) unsigned short hb[64 * 72];    // 9.2 KB
    __shared__ __align__(16) unsigned short wot[48 * 72];   // Wo^T bf16, cols padded to 48
    __shared__ float bos[48];
    const int tid = threadIdx.x;
    const int n0 = blockIdx.x * 64;
    const int nvalid = min(64, N_NODES - n0);

    for (int i = tid; i < 48 * 72; i += 256) wot[i] = 0;
    if (tid < 48) bos[tid] = (tid < OUT_F) ? bo[tid] : 0.0f;
    __syncthreads();
    for (int i = tid; i < HID * OUT_F; i += 256) {
        int k = i / OUT_F, j = i % OUT_F;       // Wo[k][j]
        wot[j * 72 + k] = f2bf(Wo[i]);
    }

    const int feat = tid & 63;
    const float invN = 1.0f / (float)N_NODES;
    float mm = sums[feat] * invN;
    float vv = sums[HID + feat] * invN - mm * mm;
    float inv = rsqrtf(vv + BN_EPS);
    float g = gamma[feat], b = beta[feat];
    for (int idx = tid; idx < 64 * HID; idx += 256) {
        int node = idx >> 6;
        float h = 0.0f;
        if (node < nvalid) {
            int gi = (n0 + node) * HID + feat;
            float a = agg[gi];
            h = hprev[gi] + fmaxf(g * (a - mm) * inv + b, 0.0f);
        }
        hb[node * 72 + feat] = f2bf(h);
    }
    __syncthreads();

    const int lane = tid & 63, wid = tid >> 6;
    const int ml = lane & 15, gl = lane >> 4;
    const int r0 = wid * 16;

    short8 A0 = *(const short8*)&hb[(r0 + ml) * 72 + gl * 8];
    short8 A1 = *(const short8*)&hb[(r0 + ml) * 72 + 32 + gl * 8];

    #pragma unroll
    for (int ct = 0; ct < 3; ++ct) {
        short8 b0 = *(const short8*)&wot[(ct * 16 + ml) * 72 + gl * 8];
        short8 b1 = *(const short8*)&wot[(ct * 16 + ml) * 72 + 32 + gl * 8];
        f32x4 z = {0.f, 0.f, 0.f, 0.f};
        z = __builtin_amdgcn_mfma_f32_16x16x32_bf16(A0, b0, z, 0, 0, 0);
        z = __builtin_amdgcn_mfma_f32_16x16x32_bf16(A1, b1, z, 0, 0, 0);
        int col = ct * 16 + ml;
        #pragma unroll
        for (int reg = 0; reg < 4; ++reg) {
            int node = n0 + r0 + gl * 4 + reg;
            if (node < N_NODES && col < OUT_F)
                out[(size_t)node * OUT_F + col] = z[reg] + bos[col];
        }
    }
}

extern "C" void kernel_launch(void* const* d_in, const int* in_sizes, int n_in,
                              void* d_out, int out_size, void* d_ws, size_t ws_size,
                              hipStream_t stream) {
    const float* x     = (const float*)d_in[0];
    const int*   ei    = (const int*)  d_in[1];   // [2, E]: row then col
    const float* Wi    = (const float*)d_in[2];
    const float* bi    = (const float*)d_in[3];
    const float* w1    = (const float*)d_in[4];
    const float* w2    = (const float*)d_in[5];
    const float* gamma = (const float*)d_in[6];
    const float* beta  = (const float*)d_in[7];
    const float* Wo    = (const float*)d_in[8];
    const float* bo    = (const float*)d_in[9];
    float* out = (float*)d_out;

    char* ws = (char*)d_ws;
    const size_t NH  = (size_t)N_NODES * HID * sizeof(float);          // 25.6 MB
    const size_t NHB = (size_t)N_NODES * HID * sizeof(unsigned short); // 12.8 MB
    size_t off = 0;
    auto alloc = [&](size_t bytes) { void* p = ws + off; off += (bytes + 255) & ~255UL; return p; };
    int*   degInt    = (int*)  alloc(N_NODES * sizeof(int));
    int*   tmpIncl   = (int*)  alloc(N_NODES * sizeof(int));
    int*   blockSums = (int*)  alloc(SCAN_BLOCKS * sizeof(int));
    int*   blockOff  = (int*)  alloc(SCAN_BLOCKS * sizeof(int));
    int*   rowOff    = (int*)  alloc((N_NODES + 1) * sizeof(int));
    int*   cursor    = (int*)  alloc(N_NODES * sizeof(int));
    int*   srow      = (int*)  alloc(E_EDGES * sizeof(int));
    float* dinv      = (float*)alloc(N_NODES * sizeof(float));
    unsigned short* sscaled = (unsigned short*)alloc(NHB);
    unsigned short* h0bf    = (unsigned short*)alloc(NHB);
    float* agg       = (float*)alloc(NH);
    float* hprev     = (float*)alloc(NH);
    float* sums      = (float*)alloc(LAYERS * 128 * sizeof(float));
    (void)ws_size; (void)in_sizes; (void)n_in; (void)out_size;

    hipMemsetAsync(degInt, 0, N_NODES * sizeof(int), stream);
    hipMemsetAsync(sums, 0, LAYERS * 128 * sizeof(float), stream);

    k_deg_count<<<(E_EDGES + 255) / 256, 256, 0, stream>>>(ei + E_EDGES, degInt);
    k_scanA<<<SCAN_BLOCKS, 256, 0, stream>>>(degInt, tmpIncl, blockSums);
    k_scanB<<<1, 512, 0, stream>>>(blockSums, blockOff);
    k_scanC<<<SCAN_BLOCKS, 256, 0, stream>>>(degInt, tmpIncl, blockOff,
                                             rowOff, cursor, dinv);
    k_fill<<<(E_EDGES + 255) / 256, 256, 0, stream>>>(ei, cursor, srow);

    k_input<<<TILE_BLOCKS, 256, 0, stream>>>(x, Wi, bi, h0bf, hprev);

    for (int l = 0; l < LAYERS; ++l) {
        const float* sums_prev = (l > 0) ? (sums + (l - 1) * 128) : sums;
        const float* gm        = (l > 0) ? (gamma + (l - 1) * HID) : gamma;
        const float* bt        = (l > 0) ? (beta  + (l - 1) * HID) : beta;
        k_layerA<<<TILE_BLOCKS, 256, 0, stream>>>(hprev, h0bf, agg,
                                                  sums_prev, gm, bt, (l > 0),
                                                  w1 + (size_t)l * HID * HID,
                                                  w2 + (size_t)l * HID * HID,
                                                  dinv, sscaled);
        k_gather<<<2048, 256, 0, stream>>>(rowOff, srow, dinv, sscaled, agg,
                                           sums + l * 128);
    }

    k_out<<<TILE_BLOCKS, 256, 0, stream>>>(hprev, agg, sums + 3 * 128,
                                           gamma + 3 * HID, beta + 3 * HID, Wo, bo, out);
}